// Round 3
// baseline (535.153 us; speedup 1.0000x reference)
//
#include <hip/hip_runtime.h>
#include <stdint.h>

#define SEQ  20
#define H1   128
#define H2   256
#define NCLS 100000
#define NOUTB 98
#define GRID (10 + NOUTB)

#define AQ  __ATOMIC_ACQUIRE
#define RL  __ATOMIC_RELEASE
#define RX  __ATOMIC_RELAXED
#define AG  __HIP_MEMORY_SCOPE_AGENT

__device__ __forceinline__ float sigm(float x) { return 1.0f / (1.0f + __expf(-x)); }
__device__ __forceinline__ float tanhfast(float x) {
    float e = __expf(-2.0f * fabsf(x));
    float t = (1.0f - e) / (1.0f + e);
    return copysignf(t, x);
}

// Fully fused pipeline:
//   blocks 0..1   : layer-1 LSTM (fwd/bwd), publishes comb[t] per step
//   blocks 2..9   : layer-2 LSTM, 8 shards x 32 cells, consumes comb[t]
//                   as it appears, publishes fb + per-shard progress flags
//   blocks 10..107: output GEMV; prefetch Wlin to L3 while waiting on fb
// Flags padded to 128 B apart to avoid one-line ping-pong.
// amdgpu_waves_per_eu(4,4): pin allocator to the 128-VGPR bin so the
// 64-float per-thread weight slices stay register-resident (round-2's
// VGPR=60 showed the occupancy heuristic evicting them).
__global__ __launch_bounds__(1024) __attribute__((amdgpu_waves_per_eu(4, 4)))
void k_fused(
    const float* __restrict__ x,
    const float* __restrict__ h0f, const float* __restrict__ c0f,
    const float* __restrict__ h0b, const float* __restrict__ c0b,
    const float* __restrict__ WihF, const float* __restrict__ WhhF,
    const float* __restrict__ bihF, const float* __restrict__ bhhF,
    const float* __restrict__ WihB, const float* __restrict__ WhhB,
    const float* __restrict__ bihB, const float* __restrict__ bhhB,
    const float* __restrict__ Wihl, const float* __restrict__ Whhl,
    const float* __restrict__ bihl, const float* __restrict__ bhhl,
    const float* __restrict__ h0l,  const float* __restrict__ c0l,
    const float* __restrict__ Wlin, const float* __restrict__ blin,
    float* __restrict__ comb, float* __restrict__ fb,
    float* __restrict__ hg2, int* __restrict__ flags,
    float* __restrict__ out)
{
    const int b   = blockIdx.x;
    const int tid = threadIdx.x;

    if (b < 2) {
        // ================= layer-1: one block per direction ===============
        const int dir = b;
        const float* Wih = dir ? WihB : WihF;
        const float* Whh = dir ? WhhB : WhhF;
        const float* bih = dir ? bihB : bihF;
        const float* bhh = dir ? bhhB : bhhF;
        const float* h0  = dir ? h0b  : h0f;
        const float* c0  = dir ? c0b  : c0f;

        __shared__ float xs[SEQ * H1];            // 10240 B
        __shared__ float hcur[H1];                //   512 B
        __shared__ float biasL[4 * H1];           //  2048 B
        __shared__ float gxs[4 * H1][SEQ + 1];    // 43008 B (stride 21)
        __shared__ float partial[4 * 520];        //  8320 B

        for (int i = tid; i < SEQ * H1; i += 1024) xs[i] = x[i];
        if (tid < 4 * H1) biasL[tid] = bih[tid] + bhh[tid];
        if (tid < H1) hcur[tid] = h0[tid];
        float cregA = 0.f, cregB = 0.f;
        if (tid < 64) { cregA = c0[tid]; cregB = c0[tid + 64]; }

        // ---- barrier-free prologue: thread = (row pr, half ph) ----
        const int pr = tid >> 1, ph = tid & 1;
        {
            float4 wf[16];
            const float4* p = (const float4*)(Wih + pr * H1 + ph * 64);
#pragma unroll
            for (int j = 0; j < 16; ++j) wf[j] = p[j];
            __syncthreads();
            for (int t = 0; t < SEQ; ++t) {
                const int tx = dir ? (SEQ - 1 - t) : t;
                const float4* xp = (const float4*)(xs + tx * H1 + ph * 64);
                float a = 0.f;
#pragma unroll
                for (int j = 0; j < 16; ++j) {
                    float4 v = xp[j];
                    a += wf[j].x * v.x + wf[j].y * v.y + wf[j].z * v.z + wf[j].w * v.w;
                }
                a += __shfl_xor(a, 1);
                if (ph == 0) gxs[pr][t] = a + biasL[pr];
            }
        }
        asm volatile("" ::: "memory");

        // ---- recurrence weights -> registers ----
        const int cg = tid >> 8, rp = tid & 255, r0 = rp * 2;
        float4 wa[8], wb[8];
        {
            const float4* pa = (const float4*)(Whh + r0 * H1 + cg * 32);
            const float4* pb = (const float4*)(Whh + (r0 + 1) * H1 + cg * 32);
#pragma unroll
            for (int j = 0; j < 8; ++j) { wa[j] = pa[j]; wb[j] = pb[j]; }
        }
        __syncthreads();

        for (int t = 0; t < SEQ; ++t) {
            const float4* hp = (const float4*)(hcur + cg * 32);   // broadcast
            float a0 = 0.f, a1 = 0.f;
#pragma unroll
            for (int j = 0; j < 8; ++j) {
                float4 v = hp[j];
                a0 += wa[j].x * v.x + wa[j].y * v.y + wa[j].z * v.z + wa[j].w * v.w;
                a1 += wb[j].x * v.x + wb[j].y * v.y + wb[j].z * v.z + wb[j].w * v.w;
            }
            *(float2*)(partial + cg * 520 + r0) = make_float2(a0, a1);
            __syncthreads();
            if (tid < 64) {
                const int c = tid;
                float s0[4], s1[4];
#pragma unroll
                for (int g = 0; g < 4; ++g) {
                    float accA = gxs[g * H1 + c][t];
                    float accB = gxs[g * H1 + c + 64][t];
#pragma unroll
                    for (int q = 0; q < 4; ++q) {
                        accA += partial[q * 520 + g * H1 + c];
                        accB += partial[q * 520 + g * H1 + c + 64];
                    }
                    s0[g] = accA; s1[g] = accB;
                }
                float cnA = sigm(s0[1]) * cregA + sigm(s0[0]) * tanhfast(s0[2]);
                float cnB = sigm(s1[1]) * cregB + sigm(s1[0]) * tanhfast(s1[2]);
                cregA = cnA; cregB = cnB;
                float hA = sigm(s0[3]) * tanhfast(cnA);
                float hB = sigm(s1[3]) * tanhfast(cnB);
                hcur[c] = hA; hcur[c + 64] = hB;
                __hip_atomic_store(&comb[t * H2 + dir * H1 + c],      hA, RX, AG);
                __hip_atomic_store(&comb[t * H2 + dir * H1 + c + 64], hB, RX, AG);
                __threadfence();
                if (tid == 0)
                    __hip_atomic_store(&flags[dir * 32], t + 1, RL, AG);
            }
            __syncthreads();
        }
    } else if (b < 10) {
        // ================= layer-2: 8 shards x 32 cells ===================
        const int s = b - 2;
        __shared__ float ct[H2];                  //  1024 B
        __shared__ float hc2[H2];                 //  1024 B
        __shared__ float bias2[128];              //   512 B
        __shared__ float part2[8 * 132];          //  4224 B

        const int cg = tid >> 7;                  // 0..7, wave-uniform
        const int L  = tid & 127;                 // local gate row
        const int R  = (L >> 5) * H2 + s * 32 + (L & 31);

        float4 wih[8], whh[8];
        {
            const float4* pi = (const float4*)(Wihl + (size_t)R * H2 + cg * 32);
            const float4* pw = (const float4*)(Whhl + (size_t)R * H2 + cg * 32);
#pragma unroll
            for (int j = 0; j < 8; ++j) { wih[j] = pi[j]; whh[j] = pw[j]; }
        }
        if (tid < 128) bias2[tid] = bihl[R] + bhhl[R];
        if (tid < H2)  hc2[tid] = h0l[tid];
        float creg = (tid < 32) ? c0l[s * 32 + tid] : 0.0f;
        __syncthreads();

        for (int t = 0; t < SEQ; ++t) {
            if (tid < 64) {
                // wait for comb[t] (both directions), then stage it
                while (true) {
                    int f0 = __hip_atomic_load(&flags[0],  AQ, AG);
                    int f1 = __hip_atomic_load(&flags[32], AQ, AG);
                    if (f0 > t && f1 > t) break;
                    __builtin_amdgcn_s_sleep(1);
                }
#pragma unroll
                for (int j = 0; j < 4; ++j)
                    ct[tid * 4 + j] = __hip_atomic_load(&comb[t * H2 + tid * 4 + j], RX, AG);
            }
            __syncthreads();
            {
                const float4* cp = (const float4*)(ct  + cg * 32);   // broadcast
                const float4* hp = (const float4*)(hc2 + cg * 32);   // broadcast
                float a = 0.f;
#pragma unroll
                for (int j = 0; j < 8; ++j) {
                    float4 cv = cp[j], hv = hp[j];
                    a += wih[j].x * cv.x + wih[j].y * cv.y + wih[j].z * cv.z + wih[j].w * cv.w
                       + whh[j].x * hv.x + whh[j].y * hv.y + whh[j].z * hv.z + whh[j].w * hv.w;
                }
                part2[cg * 132 + L] = a;
            }
            __syncthreads();
            if (tid < 32) {
                float sg[4];
#pragma unroll
                for (int g = 0; g < 4; ++g) {
                    float acc = bias2[g * 32 + tid];
#pragma unroll
                    for (int q = 0; q < 8; ++q) acc += part2[q * 132 + g * 32 + tid];
                    sg[g] = acc;
                }
                float cn = sigm(sg[1]) * creg + sigm(sg[0]) * tanhfast(sg[2]);
                creg = cn;
                float hn = sigm(sg[3]) * tanhfast(cn);
                hc2[s * 32 + tid] = hn;
                __hip_atomic_store(&fb[t * H2 + s * 32 + tid],  hn, RX, AG);
                __hip_atomic_store(&hg2[s * 32 + tid],          hn, RX, AG);
                __threadfence();
                if (tid == 0)
                    __hip_atomic_store(&flags[(2 + s) * 32], t + 1, RL, AG);
            } else if (tid >= 64 && tid < 288) {
                // pull the 224 remote h values (skip own [s*32, s*32+32))
                const int idx = (s * 32 + tid - 32) & 255;
                const int sh  = idx >> 5;
                while (__hip_atomic_load(&flags[(2 + sh) * 32], AQ, AG) <= t)
                    __builtin_amdgcn_s_sleep(1);
                hc2[idx] = __hip_atomic_load(&hg2[idx], RX, AG);
            }
            __syncthreads();
        }
    } else {
        // ================= output GEMV (98 blocks x 1024 classes) =========
        const int ob = b - 10;
        const int n  = ob * 1024 + tid;
        __shared__ __align__(16) float fbs[H2][SEQ];

        // prefetch own Wlin rows into L3 while LSTMs run (1 dword / 64B line)
        float keep = 0.f;
        if (n < NCLS) {
            const float4* wp4 = (const float4*)(Wlin + (size_t)n * H2);
#pragma unroll
            for (int j = 0; j < 64; j += 4) keep += wp4[j].x;
        }
        asm volatile("" :: "v"(keep));

        if (tid < 8) {
            while (__hip_atomic_load(&flags[(2 + tid) * 32], AQ, AG) < SEQ)
                __builtin_amdgcn_s_sleep(4);
        }
        __syncthreads();
        if (tid < H2) {
            for (int t = 0; t < SEQ; ++t)
                fbs[tid][t] = __hip_atomic_load(&fb[t * H2 + tid], RX, AG);
        }
        __syncthreads();
        if (n >= NCLS) return;

        float acc[SEQ];
        float bv = blin[n];
#pragma unroll
        for (int t = 0; t < SEQ; ++t) acc[t] = bv;

        const float* wp = Wlin + (size_t)n * H2;
        for (int k = 0; k < H2; k += 4) {
            float4 wv = *(const float4*)(wp + k);
#pragma unroll
            for (int t = 0; t < SEQ; t += 4) {
                float4 f0 = *(const float4*)(&fbs[k][t]);
                float4 f1 = *(const float4*)(&fbs[k + 1][t]);
                float4 f2 = *(const float4*)(&fbs[k + 2][t]);
                float4 f3 = *(const float4*)(&fbs[k + 3][t]);
                acc[t]     += wv.x * f0.x + wv.y * f1.x + wv.z * f2.x + wv.w * f3.x;
                acc[t + 1] += wv.x * f0.y + wv.y * f1.y + wv.z * f2.y + wv.w * f3.y;
                acc[t + 2] += wv.x * f0.z + wv.y * f1.z + wv.z * f2.z + wv.w * f3.z;
                acc[t + 3] += wv.x * f0.w + wv.y * f1.w + wv.z * f2.w + wv.w * f3.w;
            }
        }
#pragma unroll
        for (int t = 0; t < SEQ; ++t)
            out[(size_t)t * NCLS + n] = acc[t];
    }
}

// ---------------------------------------------------------------------------
extern "C" void kernel_launch(void* const* d_in, const int* in_sizes, int n_in,
                              void* d_out, int out_size, void* d_ws, size_t ws_size,
                              hipStream_t stream)
{
    const float* x    = (const float*)d_in[0];
    const float* h0f_ = (const float*)d_in[1];
    const float* c0f_ = (const float*)d_in[2];
    const float* h0b_ = (const float*)d_in[3];
    const float* c0b_ = (const float*)d_in[4];
    const float* h0l_ = (const float*)d_in[5];
    const float* c0l_ = (const float*)d_in[6];
    const float* WihF = (const float*)d_in[7];
    const float* WhhF = (const float*)d_in[8];
    const float* bihF = (const float*)d_in[9];
    const float* bhhF = (const float*)d_in[10];
    const float* WihB = (const float*)d_in[11];
    const float* WhhB = (const float*)d_in[12];
    const float* bihB = (const float*)d_in[13];
    const float* bhhB = (const float*)d_in[14];
    const float* Wihl = (const float*)d_in[15];
    const float* Whhl = (const float*)d_in[16];
    const float* bihl = (const float*)d_in[17];
    const float* bhhl = (const float*)d_in[18];
    const float* Wlin = (const float*)d_in[19];
    const float* blin = (const float*)d_in[20];

    char* ws = (char*)d_ws;
    int*   flags = (int*)ws;                     // 10 flags, 128-B apart (2048 B)
    float* hg2   = (float*)(ws + 2048);          // [256]
    float* comb  = (float*)(ws + 4096);          // [20][256]
    float* fb    = (float*)(ws + 24576);         // [20][256]

    hipMemsetAsync(flags, 0, 2048, stream);

    k_fused<<<GRID, 1024, 0, stream>>>(
        x, h0f_, c0f_, h0b_, c0b_,
        WihF, WhhF, bihF, bhhF,
        WihB, WhhB, bihB, bhhB,
        Wihl, Whhl, bihl, bhhl,
        h0l_, c0l_, Wlin, blin,
        comb, fb, hg2, flags, (float*)d_out);
}